// Round 8
// baseline (99.616 us; speedup 1.0000x reference)
//
#include <hip/hip_runtime.h>

// Problem constants: B=4, Nc=1024, Nf=8192, fp32 in/out.
#define B  4
#define NF 8192
#define NC 1024
#define TJ (NF / 32)          // 256 col-tiles per batch
#define BANDS 128             // 64-row bands per batch
#define TPW 32                // col-tiles per wave (8 waves/block)
#define NCRS (B * NC)

typedef _Float16 h8   __attribute__((ext_vector_type(8)));
typedef float    f16v __attribute__((ext_vector_type(16)));

// ---------------------------------------------------------------------------
// Two-pass rows-only MFMA chamfer (validated rounds 6-7, absmax 0.0).
// d(i,j) computed ENTIRELY inside one mfma_f32_32x32x16_f16 via augmented
// K-slots (fp16 hi/lo splits):
//   A k: [xh0 xh1 xh2 xl0 xl1 xl2 xh0 xh1 | xh2 sxh sxl 1 1 0 0 0]
//   B k: [mh0 mh1 mh2 mh0 mh1 mh2 ml0 ml1 | ml2 1 1 syh syl 0 0 0]
// with m = -2y (hi+lo), s = |.|^2 (hi+lo):  acc[r] ~= d  (err ~2^-21).
// Round 8: TWO kernel nodes total. k_prep block 512 computes the coarse loss
// and initializes out (kills the memset node); k_main blocks atomicAdd their
// pre-scaled fine partials straight into out[1] (kills k_reduce + rowbuf).
// Dispatch-gap overhead ~5us/node is now the dominant controllable cost.
// ---------------------------------------------------------------------------

__global__ __launch_bounds__(256) void k_prep(const float* __restrict__ rf,
                                              const float* __restrict__ gf,
                                              const float* __restrict__ rc,
                                              const float* __restrict__ gc,
                                              h8* __restrict__ fragbuf,
                                              float* __restrict__ out) {
    if (blockIdx.x == 512) {
        // ---- coarse L2 loss + out init (one block) ----
        int t = threadIdx.x;
        float s = 0.0f;
        for (int i = t; i < NCRS; i += 256) {
            float dx = rc[3 * i + 0] - gc[3 * i + 0];
            float dy = rc[3 * i + 1] - gc[3 * i + 1];
            float dz = rc[3 * i + 2] - gc[3 * i + 2];
            s += sqrtf(fmaf(dx, dx, fmaf(dy, dy, dz * dz)));
        }
#pragma unroll
        for (int off = 32; off > 0; off >>= 1) s += __shfl_down(s, off);
        __shared__ float red[4];
        int lane = t & 63, w = t >> 6;
        if (lane == 0) red[w] = s;
        __syncthreads();
        if (t == 0) {
            out[0] = (red[0] + red[1] + red[2] + red[3]) * (1.0f / (float)NCRS);
            out[1] = 0.0f;   // k_main accumulates here (stream-ordered)
        }
        return;
    }

    // ---- B-fragment build: src 0 = gf, src 1 = rf ----
    int id  = blockIdx.x * 256 + threadIdx.x;   // 131072 total
    int src = id >> 16;
    int rem = id & 65535;
    int b   = rem >> 14;
    int jt  = (rem >> 6) & (TJ - 1);
    int ln  = rem & 63;
    int n   = ln & 31, kg = ln >> 5;

    const float* y = (src ? rf : gf) + ((size_t)(b * NF) + jt * 32 + n) * 3;
    float y0 = y[0], y1 = y[1], y2 = y[2];
    float t0 = -2.0f * y0, t1 = -2.0f * y1, t2 = -2.0f * y2;
    _Float16 mh0 = (_Float16)t0, mh1 = (_Float16)t1, mh2 = (_Float16)t2;
    _Float16 ml0 = (_Float16)(t0 - (float)mh0);
    _Float16 ml1 = (_Float16)(t1 - (float)mh1);
    _Float16 ml2 = (_Float16)(t2 - (float)mh2);
    float sy = fmaf(y0, y0, fmaf(y1, y1, y2 * y2));
    _Float16 syh = (_Float16)sy;
    _Float16 syl = (_Float16)(sy - (float)syh);

    h8 fr = {};
    if (kg == 0) {
        fr[0] = mh0; fr[1] = mh1; fr[2] = mh2;
        fr[3] = mh0; fr[4] = mh1; fr[5] = mh2;
        fr[6] = ml0; fr[7] = ml1;
    } else {
        fr[0] = ml2; fr[1] = (_Float16)1.0f; fr[2] = (_Float16)1.0f;
        fr[3] = syh; fr[4] = syl;
    }
    fragbuf[((size_t)(src * B + b) * TJ + jt) * 64 + ln] = fr;
}

__global__ __launch_bounds__(512) void k_main(const float* __restrict__ rf,
                                              const float* __restrict__ gf,
                                              const h8* __restrict__ fragbuf,
                                              float* __restrict__ out) {
    __shared__ float rbuf[8][64];

    int bx   = blockIdx.x;      // 1024 = 2 dirs * 4 batches * 128 bands
    int dir  = bx >> 9;
    int rem  = bx & 511;
    int b    = rem >> 7;
    int band = rem & 127;
    int t  = threadIdx.x;
    int ln = t & 63, w = t >> 6, m = ln & 31, kg = ln >> 5;

    // ---- A fragments for the block's 64 rows (2 per wave, wave-redundant) --
    const float* xp = dir ? gf : rf;
    h8 afr[2];
#pragma unroll
    for (int f = 0; f < 2; ++f) {
        const float* xr = xp + ((size_t)(b * NF) + band * 64 + f * 32 + m) * 3;
        float x0 = xr[0], x1 = xr[1], x2 = xr[2];
        _Float16 h0 = (_Float16)x0, h1 = (_Float16)x1, h2 = (_Float16)x2;
        _Float16 l0 = (_Float16)(x0 - (float)h0);
        _Float16 l1 = (_Float16)(x1 - (float)h1);
        _Float16 l2 = (_Float16)(x2 - (float)h2);
        float sx = fmaf(x0, x0, fmaf(x1, x1, x2 * x2));
        _Float16 sh = (_Float16)sx;
        _Float16 sl = (_Float16)(sx - (float)sh);
        h8 fr = {};
        if (kg == 0) {
            fr[0] = h0; fr[1] = h1; fr[2] = h2;
            fr[3] = l0; fr[4] = l1; fr[5] = l2;
            fr[6] = h0; fr[7] = h1;
        } else {
            fr[0] = h2; fr[1] = sh; fr[2] = sl;
            fr[3] = (_Float16)1.0f; fr[4] = (_Float16)1.0f;
        }
        afr[f] = fr;
    }

    float rmin0[16], rmin1[16];
#pragma unroll
    for (int r = 0; r < 16; ++r) { rmin0[r] = 3.4e38f; rmin1[r] = 3.4e38f; }

    // ---- main loop: wave w owns col-tile pairs; per pair:
    //      2 loads (prefetched) + 4 MFMA + 32 v_min3_f32.
    const h8* p = fragbuf + ((size_t)(dir * B + b) * TJ + w * TPW) * 64 + ln;
    h8 b0 = p[0];
    h8 b1 = p[64];
#pragma unroll 2
    for (int q = 0; q < TPW / 2; ++q) {
        // Unconditional prefetch of the next pair (fragbuf tail-padded 2KB).
        h8 n0 = p[(2 * q + 2) * 64];
        h8 n1 = p[(2 * q + 3) * 64];
        f16v c00 = __builtin_amdgcn_mfma_f32_32x32x16_f16(afr[0], b0, (f16v){}, 0, 0, 0);
        f16v c01 = __builtin_amdgcn_mfma_f32_32x32x16_f16(afr[0], b1, (f16v){}, 0, 0, 0);
#pragma unroll
        for (int r = 0; r < 16; ++r)
            rmin0[r] = fminf(fminf(c00[r], c01[r]), rmin0[r]);   // v_min3_f32
        f16v c10 = __builtin_amdgcn_mfma_f32_32x32x16_f16(afr[1], b0, (f16v){}, 0, 0, 0);
        f16v c11 = __builtin_amdgcn_mfma_f32_32x32x16_f16(afr[1], b1, (f16v){}, 0, 0, 0);
#pragma unroll
        for (int r = 0; r < 16; ++r)
            rmin1[r] = fminf(fminf(c10[r], c11[r]), rmin1[r]);
        b0 = n0;
        b1 = n1;
    }

    // ---- epilogue: min over cols (lanes within half-wave), then waves ----
#pragma unroll
    for (int off = 1; off <= 16; off <<= 1) {
#pragma unroll
        for (int r = 0; r < 16; ++r) {
            rmin0[r] = fminf(rmin0[r], __shfl_xor(rmin0[r], off));
            rmin1[r] = fminf(rmin1[r], __shfl_xor(rmin1[r], off));
        }
    }
    if (m == 0) {   // lanes 0 (kg=0) and 32 (kg=1): disjoint row sets
#pragma unroll
        for (int r = 0; r < 16; ++r) {
            int row = 4 * kg + (r & 3) + 8 * (r >> 2);   // C/D map (m74/m101)
            rbuf[w][row]      = rmin0[r];
            rbuf[w][32 + row] = rmin1[r];
        }
    }
    __syncthreads();
    // Final: 64 row-mins -> sqrt -> sum -> ONE pre-scaled atomicAdd per block.
    if (t < 64) {   // wave 0
        float v = rbuf[0][t];
#pragma unroll
        for (int ww = 1; ww < 8; ++ww) v = fminf(v, rbuf[ww][t]);
        v = sqrtf(fmaxf(v, 0.0f));
#pragma unroll
        for (int off = 32; off > 0; off >>= 1) v += __shfl_down(v, off);
        if (t == 0) atomicAdd(&out[1], v * (0.5f / (float)(B * NF)));
    }
}

extern "C" void kernel_launch(void* const* d_in, const int* in_sizes, int n_in,
                              void* d_out, int out_size, void* d_ws, size_t ws_size,
                              hipStream_t stream) {
    const float* rc = (const float*)d_in[0];  // ret_coarse [4,1024,3]
    const float* rf = (const float*)d_in[1];  // ret_fine   [4,8192,3]
    const float* gf = (const float*)d_in[2];  // gt_fine    [4,8192,3]
    const float* gc = (const float*)d_in[3];  // gt_coarse  [4,1024,3]

    h8*    fragbuf = (h8*)d_ws;               // 2 MB (+2 KB prefetch pad)
    float* out     = (float*)d_out;

    k_prep<<<513, 256, 0, stream>>>(rf, gf, rc, gc, fragbuf, out);
    k_main<<<2 * B * BANDS, 512, 0, stream>>>(rf, gf, fragbuf, out);
}

// Round 9
// 96.110 us; speedup vs baseline: 1.0365x; 1.0365x over previous
//
#include <hip/hip_runtime.h>

// Problem constants: B=4, Nc=1024, Nf=8192, fp32 in/out.
#define B  4
#define NF 8192
#define NC 1024
#define TJ (NF / 32)          // 256 col-tiles per batch
#define BANDS 128             // 64-row bands per batch
#define TPW 32                // col-tiles per wave (8 waves/block)

#define NMIN (2 * B * NF)     // 65536 per-point NN sqrt-dists
#define NCRS (B * NC)
#define NTOT (NMIN + NCRS)

typedef _Float16 h8   __attribute__((ext_vector_type(8)));
typedef float    f16v __attribute__((ext_vector_type(16)));

// ---------------------------------------------------------------------------
// Two-pass rows-only MFMA chamfer (validated rounds 6-8, absmax 0.0).
// d(i,j) computed ENTIRELY inside one mfma_f32_32x32x16_f16 via augmented
// K-slots (fp16 hi/lo splits):
//   A k: [xh0 xh1 xh2 xl0 xl1 xl2 xh0 xh1 | xh2 sxh sxl 1 1 0 0 0]
//   B k: [mh0 mh1 mh2 mh0 mh1 mh2 ml0 ml1 | ml2 1 1 syh syl 0 0 0]
// with m = -2y (hi+lo), s = |.|^2 (hi+lo):  acc[r] ~= d  (err ~2^-21).
// Round 9: exact revert to the round-7 structure (best measured, 94.4 us).
// Round 8's fusion (coarse loss inside k_prep + per-block atomicAdd into
// d_out) regressed to 99.6 us -> separate cheap k_reduce wins. Total is now
// dominated by fixed harness overhead (268 MB ws-poison fill ~41 us at 82%
// HBM peak + restore/replay ~45 us); our kernels are ~10 us combined.
// ---------------------------------------------------------------------------

// Build B fragments for both point sets: src 0 = gf, src 1 = rf.
__global__ __launch_bounds__(256) void k_prep(const float* __restrict__ rf,
                                              const float* __restrict__ gf,
                                              h8* __restrict__ fragbuf) {
    int id  = blockIdx.x * 256 + threadIdx.x;   // 131072 total
    int src = id >> 16;
    int rem = id & 65535;
    int b   = rem >> 14;
    int jt  = (rem >> 6) & (TJ - 1);
    int ln  = rem & 63;
    int n   = ln & 31, kg = ln >> 5;

    const float* y = (src ? rf : gf) + ((size_t)(b * NF) + jt * 32 + n) * 3;
    float y0 = y[0], y1 = y[1], y2 = y[2];
    float t0 = -2.0f * y0, t1 = -2.0f * y1, t2 = -2.0f * y2;
    _Float16 mh0 = (_Float16)t0, mh1 = (_Float16)t1, mh2 = (_Float16)t2;
    _Float16 ml0 = (_Float16)(t0 - (float)mh0);
    _Float16 ml1 = (_Float16)(t1 - (float)mh1);
    _Float16 ml2 = (_Float16)(t2 - (float)mh2);
    float sy = fmaf(y0, y0, fmaf(y1, y1, y2 * y2));
    _Float16 syh = (_Float16)sy;
    _Float16 syl = (_Float16)(sy - (float)syh);

    h8 fr = {};
    if (kg == 0) {
        fr[0] = mh0; fr[1] = mh1; fr[2] = mh2;
        fr[3] = mh0; fr[4] = mh1; fr[5] = mh2;
        fr[6] = ml0; fr[7] = ml1;
    } else {
        fr[0] = ml2; fr[1] = (_Float16)1.0f; fr[2] = (_Float16)1.0f;
        fr[3] = syh; fr[4] = syl;
    }
    fragbuf[((size_t)(src * B + b) * TJ + jt) * 64 + ln] = fr;
}

__global__ __launch_bounds__(512) void k_main(const float* __restrict__ rf,
                                              const float* __restrict__ gf,
                                              const h8* __restrict__ fragbuf,
                                              float* __restrict__ rowbuf) {
    __shared__ float rbuf[8][64];

    int bx   = blockIdx.x;      // 1024 = 2 dirs * 4 batches * 128 bands
    int dir  = bx >> 9;
    int rem  = bx & 511;
    int b    = rem >> 7;
    int band = rem & 127;
    int t  = threadIdx.x;
    int ln = t & 63, w = t >> 6, m = ln & 31, kg = ln >> 5;

    // ---- A fragments for the block's 64 rows (2 per wave, wave-redundant) --
    const float* xp = dir ? gf : rf;
    h8 afr[2];
#pragma unroll
    for (int f = 0; f < 2; ++f) {
        const float* xr = xp + ((size_t)(b * NF) + band * 64 + f * 32 + m) * 3;
        float x0 = xr[0], x1 = xr[1], x2 = xr[2];
        _Float16 h0 = (_Float16)x0, h1 = (_Float16)x1, h2 = (_Float16)x2;
        _Float16 l0 = (_Float16)(x0 - (float)h0);
        _Float16 l1 = (_Float16)(x1 - (float)h1);
        _Float16 l2 = (_Float16)(x2 - (float)h2);
        float sx = fmaf(x0, x0, fmaf(x1, x1, x2 * x2));
        _Float16 sh = (_Float16)sx;
        _Float16 sl = (_Float16)(sx - (float)sh);
        h8 fr = {};
        if (kg == 0) {
            fr[0] = h0; fr[1] = h1; fr[2] = h2;
            fr[3] = l0; fr[4] = l1; fr[5] = l2;
            fr[6] = h0; fr[7] = h1;
        } else {
            fr[0] = h2; fr[1] = sh; fr[2] = sl;
            fr[3] = (_Float16)1.0f; fr[4] = (_Float16)1.0f;
        }
        afr[f] = fr;
    }

    float rmin0[16], rmin1[16];
#pragma unroll
    for (int r = 0; r < 16; ++r) { rmin0[r] = 3.4e38f; rmin1[r] = 3.4e38f; }

    // ---- main loop: wave w owns col-tile pairs; per pair:
    //      2 loads (prefetched) + 4 MFMA + 32 v_min3_f32.
    const h8* p = fragbuf + ((size_t)(dir * B + b) * TJ + w * TPW) * 64 + ln;
    h8 b0 = p[0];
    h8 b1 = p[64];
#pragma unroll 2
    for (int q = 0; q < TPW / 2; ++q) {
        // Unconditional prefetch of the next pair (fragbuf tail-padded 2KB).
        h8 n0 = p[(2 * q + 2) * 64];
        h8 n1 = p[(2 * q + 3) * 64];
        f16v c00 = __builtin_amdgcn_mfma_f32_32x32x16_f16(afr[0], b0, (f16v){}, 0, 0, 0);
        f16v c01 = __builtin_amdgcn_mfma_f32_32x32x16_f16(afr[0], b1, (f16v){}, 0, 0, 0);
#pragma unroll
        for (int r = 0; r < 16; ++r)
            rmin0[r] = fminf(fminf(c00[r], c01[r]), rmin0[r]);   // v_min3_f32
        f16v c10 = __builtin_amdgcn_mfma_f32_32x32x16_f16(afr[1], b0, (f16v){}, 0, 0, 0);
        f16v c11 = __builtin_amdgcn_mfma_f32_32x32x16_f16(afr[1], b1, (f16v){}, 0, 0, 0);
#pragma unroll
        for (int r = 0; r < 16; ++r)
            rmin1[r] = fminf(fminf(c10[r], c11[r]), rmin1[r]);
        b0 = n0;
        b1 = n1;
    }

    // ---- epilogue: min over cols (lanes within half-wave), then waves ----
#pragma unroll
    for (int off = 1; off <= 16; off <<= 1) {
#pragma unroll
        for (int r = 0; r < 16; ++r) {
            rmin0[r] = fminf(rmin0[r], __shfl_xor(rmin0[r], off));
            rmin1[r] = fminf(rmin1[r], __shfl_xor(rmin1[r], off));
        }
    }
    if (m == 0) {   // lanes 0 (kg=0) and 32 (kg=1): disjoint row sets
#pragma unroll
        for (int r = 0; r < 16; ++r) {
            int row = 4 * kg + (r & 3) + 8 * (r >> 2);   // C/D map (m74/m101)
            rbuf[w][row]      = rmin0[r];
            rbuf[w][32 + row] = rmin1[r];
        }
    }
    __syncthreads();
    if (t < 64) {
        float v = rbuf[0][t];
#pragma unroll
        for (int ww = 1; ww < 8; ++ww) v = fminf(v, rbuf[ww][t]);
        rowbuf[(size_t)dir * (B * NF) + b * NF + band * 64 + t] =
            sqrtf(fmaxf(v, 0.0f));
    }
}

__global__ __launch_bounds__(256) void k_reduce(const float* __restrict__ rowbuf,
                                                const float* __restrict__ rc,
                                                const float* __restrict__ gc,
                                                float* __restrict__ out) {
    float s_crs = 0.f, s_fine = 0.f;
    for (int i = blockIdx.x * 256 + threadIdx.x; i < NTOT; i += gridDim.x * 256) {
        if (i < NMIN) {
            s_fine += rowbuf[i];                     // already sqrt'd
        } else {
            int pnt = i - NMIN;
            float dx = rc[3 * pnt + 0] - gc[3 * pnt + 0];
            float dy = rc[3 * pnt + 1] - gc[3 * pnt + 1];
            float dz = rc[3 * pnt + 2] - gc[3 * pnt + 2];
            s_crs += sqrtf(fmaf(dx, dx, fmaf(dy, dy, dz * dz)));
        }
    }
#pragma unroll
    for (int off = 32; off > 0; off >>= 1) {
        s_crs  += __shfl_down(s_crs, off);
        s_fine += __shfl_down(s_fine, off);
    }
    __shared__ float red[2][4];
    int lane = threadIdx.x & 63, w = threadIdx.x >> 6;
    if (lane == 0) { red[0][w] = s_crs; red[1][w] = s_fine; }
    __syncthreads();
    if (threadIdx.x == 0) {
        float t0 = red[0][0] + red[0][1] + red[0][2] + red[0][3];
        float t1 = red[1][0] + red[1][1] + red[1][2] + red[1][3];
        atomicAdd(&out[0], t0 * (1.0f / (float)NCRS));     // loss_coarse
        atomicAdd(&out[1], t1 * (0.5f / (float)(B * NF))); // loss_fine
    }
}

extern "C" void kernel_launch(void* const* d_in, const int* in_sizes, int n_in,
                              void* d_out, int out_size, void* d_ws, size_t ws_size,
                              hipStream_t stream) {
    const float* rc = (const float*)d_in[0];  // ret_coarse [4,1024,3]
    const float* rf = (const float*)d_in[1];  // ret_fine   [4,8192,3]
    const float* gf = (const float*)d_in[2];  // gt_fine    [4,8192,3]
    const float* gc = (const float*)d_in[3];  // gt_coarse  [4,1024,3]

    float* rowbuf  = (float*)d_ws;                           // 256 KB
    h8*    fragbuf = (h8*)((char*)d_ws + (size_t)NMIN * 4);  // 2 MB (+2KB pad
    float* out     = (float*)d_out;                          //  for prefetch)

    hipMemsetAsync(out, 0, 2 * sizeof(float), stream);
    k_prep<<<512, 256, 0, stream>>>(rf, gf, fragbuf);
    k_main<<<2 * B * BANDS, 512, 0, stream>>>(rf, gf, fragbuf, rowbuf);
    k_reduce<<<64, 256, 0, stream>>>(rowbuf, rc, gc, out);
}